// Round 1
// baseline (135.398 us; speedup 1.0000x reference)
//
#include <hip/hip_runtime.h>

// MultiAgentLinearLayer: out[b,o] = sum_k W[agent[b],o,k] * x[b,k] + bias[agent[b],o]
// B=2048, I=O=512, 64 agents, fp32.
//
// Strategy: group rows by agent so each agent's 1MB weight slice is streamed
// from HBM once and reused across its ~32 rows. Each block does its own
// deterministic (stable) compaction of the row list for its agent in LDS --
// avoids a serial sort kernel and any workspace, and guarantees z-split
// blocks see an identical row ordering.
// Block = (out-tile of 128, agent, chunk-slot). fp32 register-tiled GEMM:
// TM=32 rows x TN=128 outs, BK=32, 4x4 micro-tile per thread (256 threads),
// float4 global loads, ds_read_b128 LDS reads, LDS stride 36 floats
// (stride%32==4 -> b128 reads tile the 32 banks with no extra conflicts).

constexpr int BATCH  = 2048;
constexpr int NAGENT = 64;
constexpr int IN_F   = 512;
constexpr int OUT_F  = 512;

constexpr int TM   = 32;
constexpr int TN   = 128;
constexpr int BK   = 32;
constexpr int LDSS = BK + 4;   // float stride; rows stay 16B-aligned
constexpr int ZCH  = 2;        // row-chunk slots in grid.z (stride loop covers adversarial counts)

__global__ __launch_bounds__(256, 2) void agent_linear(
    const int*   __restrict__ which,
    const float* __restrict__ x,
    const float* __restrict__ weight,
    const float* __restrict__ bias,
    float*       __restrict__ out) {
  const int tid    = threadIdx.x;
  const int agent  = blockIdx.y;
  const int o_base = blockIdx.x * TN;

  __shared__ int rowlist_s[BATCH];          // 8 KB
  __shared__ int scan_s[256];               // 1 KB
  __shared__ __align__(16) float Xs[TM * LDSS];   // 4.6 KB
  __shared__ __align__(16) float Ws[TN * LDSS];   // 18.4 KB

  // ---- stable compaction: rows with which[i]==agent, in ascending order ----
  int vals[8];
  {
    const int4* w4 = (const int4*)which;
    int4 v0 = w4[tid * 2];
    int4 v1 = w4[tid * 2 + 1];
    vals[0] = v0.x; vals[1] = v0.y; vals[2] = v0.z; vals[3] = v0.w;
    vals[4] = v1.x; vals[5] = v1.y; vals[6] = v1.z; vals[7] = v1.w;
  }
  int lc = 0;
#pragma unroll
  for (int u = 0; u < 8; ++u) lc += (vals[u] == agent) ? 1 : 0;
  scan_s[tid] = lc;
  __syncthreads();
  // Hillis-Steele inclusive scan over 256 per-thread counts
#pragma unroll
  for (int off = 1; off < 256; off <<= 1) {
    int add = (tid >= off) ? scan_s[tid - off] : 0;
    __syncthreads();
    scan_s[tid] += add;
    __syncthreads();
  }
  {
    int pos = scan_s[tid] - lc;
#pragma unroll
    for (int u = 0; u < 8; ++u) {
      if (vals[u] == agent) rowlist_s[pos++] = tid * 8 + u;
    }
  }
  const int count = scan_s[255];
  __syncthreads();   // rowlist_s ready

  const float* wA = weight + (size_t)agent * OUT_F * IN_F + (size_t)o_base * IN_F;
  const float* bA = bias + agent * OUT_F + o_base;

  const int tx = tid & 31;   // n-group: n = tx + 32*j, j<4
  const int ty = tid >> 5;   // m-group: m = ty + 8*i,  i<4

  for (int m0 = blockIdx.z * TM; m0 < count; m0 += TM * ZCH) {
    const int mcount = min(TM, count - m0);

    // X staging assignment: thread -> (row, 16B column chunk)
    const int xrow = tid >> 3;  // 0..31
    const int xc4  = tid & 7;   // 0..7
    const float* xp = nullptr;
    if (xrow < mcount) xp = x + (size_t)rowlist_s[m0 + xrow] * IN_F + xc4 * 4;

    float acc[4][4] = {};

    for (int kc = 0; kc < IN_F; kc += BK) {
      __syncthreads();   // prior tile's LDS reads done before restaging
      // stage W tile: 128 rows x 32 floats (4 float4 per thread, coalesced)
#pragma unroll
      for (int it = 0; it < 4; ++it) {
        int idx = tid + 256 * it;
        int r   = idx >> 3;
        int c4  = idx & 7;
        float4 v = *(const float4*)(wA + (size_t)r * IN_F + kc + c4 * 4);
        *(float4*)(&Ws[r * LDSS + c4 * 4]) = v;
      }
      // stage X tile: 32 rows x 32 floats (1 float4 per thread); zero-pad tail rows
      {
        float4 v = {0.f, 0.f, 0.f, 0.f};
        if (xp) v = *(const float4*)(xp + kc);
        *(float4*)(&Xs[xrow * LDSS + xc4 * 4]) = v;
      }
      __syncthreads();

#pragma unroll
      for (int kk = 0; kk < BK; kk += 4) {
        float4 a[4], b[4];
#pragma unroll
        for (int i = 0; i < 4; ++i)
          a[i] = *(const float4*)(&Xs[(ty + 8 * i) * LDSS + kk]);
#pragma unroll
        for (int j = 0; j < 4; ++j)
          b[j] = *(const float4*)(&Ws[(tx + 32 * j) * LDSS + kk]);
#pragma unroll
        for (int i = 0; i < 4; ++i) {
#pragma unroll
          for (int j = 0; j < 4; ++j) {
            acc[i][j] += a[i].x * b[j].x;
            acc[i][j] += a[i].y * b[j].y;
            acc[i][j] += a[i].z * b[j].z;
            acc[i][j] += a[i].w * b[j].w;
          }
        }
      }
    }

    // epilogue: out[row, o_base + n] = acc + bias
#pragma unroll
    for (int i = 0; i < 4; ++i) {
      int m = ty + 8 * i;
      if (m < mcount) {
        float* op = out + (size_t)rowlist_s[m0 + m] * OUT_F + o_base;
#pragma unroll
        for (int j = 0; j < 4; ++j) {
          int n = tx + 32 * j;
          op[n] = acc[i][j] + bA[n];
        }
      }
    }
  }
}

extern "C" void kernel_launch(void* const* d_in, const int* in_sizes, int n_in,
                              void* d_out, int out_size, void* d_ws, size_t ws_size,
                              hipStream_t stream) {
  const int*   which = (const int*)d_in[0];
  const float* x     = (const float*)d_in[1];
  const float* w     = (const float*)d_in[2];
  const float* b     = (const float*)d_in[3];
  float*       out   = (float*)d_out;

  dim3 grid(OUT_F / TN, NAGENT, ZCH);   // 4 x 64 x 2 = 512 blocks
  agent_linear<<<grid, dim3(256), 0, stream>>>(which, x, w, b, out);
}

// Round 2
// 109.882 us; speedup vs baseline: 1.2322x; 1.2322x over previous
//
#include <hip/hip_runtime.h>

// MultiAgentLinearLayer via bf16 MFMA (threshold 5.97e-2 permits bf16).
// out[b,o] = sum_k W[agent[b],o,k]*x[b,k] + bias[agent[b],o]
// B=2048, I=O=512, 64 agents, fp32 in/out.
//
// Structure:
//  - block = (n-tile of 128, agent); 512 threads = 8 waves; grid 4x64 = 256.
//  - per-block stable compaction of rows for this agent (wave-shuffle scan).
//  - X slice for the agent staged ONCE into LDS as bf16 (64 rows x 512 k,
//    stride 520 -> ds_read_b128 A-frags are conflict-free).
//  - W streamed global->registers (B^T layout: contiguous-K 32B per lane),
//    fp32->bf16 converted in flight, 1-deep register prefetch.
//  - K-loop is completely barrier-free: MFMA 16x16x32_bf16, fp32 accum.
//  - weight read from HBM exactly once (each block owns a distinct 128-col slab).

constexpr int BATCH  = 2048;
constexpr int NAGENT = 64;
constexpr int IN_F   = 512;
constexpr int OUT_F  = 512;

constexpr int BN  = 128;        // block n-tile
constexpr int MCH = 64;         // m-chunk (rows per outer iter)
constexpr int XS  = IN_F + 8;   // X LDS stride in bf16 elems (520: %32==8 -> b128 conflict-free)

typedef __attribute__((ext_vector_type(8))) short short8;   // bf16 A/B frag (4 VGPRs)
typedef __attribute__((ext_vector_type(4))) float f32x4;    // fp32 C/D frag

__device__ inline unsigned short f2bf(float f) {
  // round-to-nearest-even fp32 -> bf16
  unsigned u = __float_as_uint(f);
  return (unsigned short)((u + 0x7FFFu + ((u >> 16) & 1u)) >> 16);
}

__global__ __launch_bounds__(512, 2) void agent_linear_mfma(
    const int*   __restrict__ which,
    const float* __restrict__ x,
    const float* __restrict__ weight,
    const float* __restrict__ bias,
    float*       __restrict__ out) {
  const int tid   = threadIdx.x;
  const int lane  = tid & 63;
  const int wid   = tid >> 6;        // 0..7
  const int agent = blockIdx.y;
  const int obase = blockIdx.x * BN;

  __shared__ int rowlist_s[BATCH];                    // 8 KB
  __shared__ int wsum_s[8];
  __shared__ __align__(16) unsigned short Xs[MCH * XS];  // 65 KB, bf16

  // ---- stable compaction: rows with which[i]==agent, ascending ----
  int4 v = ((const int4*)which)[tid];                 // 4 vals/thread, 512 threads
  int lc = (v.x == agent) + (v.y == agent) + (v.z == agent) + (v.w == agent);
  int s = lc;
#pragma unroll
  for (int off = 1; off < 64; off <<= 1) {
    int t = __shfl_up(s, off);
    if (lane >= off) s += t;
  }
  if (lane == 63) wsum_s[wid] = s;
  __syncthreads();
  int base = 0, count = 0;
#pragma unroll
  for (int w = 0; w < 8; ++w) {
    int ws = wsum_s[w];
    if (w < wid) base += ws;
    count += ws;
  }
  {
    int pos = base + s - lc;
    if (v.x == agent) rowlist_s[pos++] = 4 * tid + 0;
    if (v.y == agent) rowlist_s[pos++] = 4 * tid + 1;
    if (v.z == agent) rowlist_s[pos++] = 4 * tid + 2;
    if (v.w == agent) rowlist_s[pos++] = 4 * tid + 3;
  }
  __syncthreads();   // rowlist_s ready

  const int nl = lane & 15;      // n within frag / m within A-frag
  const int kq = lane >> 4;      // 0..3 k-quad

  const float* wp = weight + ((size_t)agent * OUT_F + obase + wid * 16 + nl) * IN_F + kq * 8;
  const float  bv = bias[agent * OUT_F + obase + wid * 16 + nl];

  for (int m0 = 0; m0 < count; m0 += MCH) {
    const int mcount = min(MCH, count - m0);

    // ---- stage X chunk into LDS as bf16: 64 rows x 512 k ----
    __syncthreads();   // protect previous iter's reads
#pragma unroll 4
    for (int it = 0; it < MCH / 4; ++it) {
      int r = it * 4 + (tid >> 7);     // 4 rows per iteration, 128 threads/row
      int c = (tid & 127) * 4;
      float4 xv = {0.f, 0.f, 0.f, 0.f};
      if (r < mcount) xv = *(const float4*)(x + (size_t)rowlist_s[m0 + r] * IN_F + c);
      unsigned lo = (unsigned)f2bf(xv.x) | ((unsigned)f2bf(xv.y) << 16);
      unsigned hi = (unsigned)f2bf(xv.z) | ((unsigned)f2bf(xv.w) << 16);
      uint2 w2 = {lo, hi};
      *(uint2*)&Xs[r * XS + c] = w2;
    }
    __syncthreads();

    // ---- barrier-free K-loop ----
    f32x4 acc[4] = {{0.f, 0.f, 0.f, 0.f}, {0.f, 0.f, 0.f, 0.f},
                    {0.f, 0.f, 0.f, 0.f}, {0.f, 0.f, 0.f, 0.f}};
    float4 b0 = *(const float4*)(wp);
    float4 b1 = *(const float4*)(wp + 4);
    for (int kc = 0; kc < IN_F; kc += 32) {
      float4 c0 = b0, c1 = b1;
      int kn = kc + 32;
      if (kn < IN_F) {
        b0 = *(const float4*)(wp + kn);
        b1 = *(const float4*)(wp + kn + 4);
      }
      short8 bf;
      bf[0] = (short)f2bf(c0.x); bf[1] = (short)f2bf(c0.y);
      bf[2] = (short)f2bf(c0.z); bf[3] = (short)f2bf(c0.w);
      bf[4] = (short)f2bf(c1.x); bf[5] = (short)f2bf(c1.y);
      bf[6] = (short)f2bf(c1.z); bf[7] = (short)f2bf(c1.w);
#pragma unroll
      for (int i = 0; i < 4; ++i) {
        short8 af = *(const short8*)&Xs[(i * 16 + nl) * XS + kc + kq * 8];
        acc[i] = __builtin_amdgcn_mfma_f32_16x16x32_bf16(af, bf, acc[i], 0, 0, 0);
      }
    }

    // ---- epilogue: D row=(lane>>4)*4+reg, col=lane&15 ----
#pragma unroll
    for (int i = 0; i < 4; ++i) {
#pragma unroll
      for (int r = 0; r < 4; ++r) {
        int ml = i * 16 + kq * 4 + r;
        if (ml < mcount) {
          int grow = rowlist_s[m0 + ml];
          out[(size_t)grow * OUT_F + obase + wid * 16 + nl] = acc[i][r] + bv;
        }
      }
    }
  }
}

extern "C" void kernel_launch(void* const* d_in, const int* in_sizes, int n_in,
                              void* d_out, int out_size, void* d_ws, size_t ws_size,
                              hipStream_t stream) {
  const int*   which = (const int*)d_in[0];
  const float* x     = (const float*)d_in[1];
  const float* w     = (const float*)d_in[2];
  const float* b     = (const float*)d_in[3];
  float*       out   = (float*)d_out;

  dim3 grid(OUT_F / BN, NAGENT);   // 4 x 64 = 256 blocks, 1/CU
  agent_linear_mfma<<<grid, dim3(512), 0, stream>>>(which, x, w, b, out);
}

// Round 3
// 107.882 us; speedup vs baseline: 1.2551x; 1.0185x over previous
//
#include <hip/hip_runtime.h>

// MultiAgentLinearLayer via bf16 MFMA, round 3: K-split wave pairs + deep prefetch.
// out[b,o] = sum_k W[agent[b],o,k]*x[b,k] + bias[agent[b],o]
// B=2048, I=O=512, 64 agents, fp32 in/out. Threshold 5.97e-2 permits bf16.
//
// Structure:
//  - block = 1024 threads = 16 waves; grid 4 n-tiles x 64 agents = 256 blocks (1/CU).
//  - waves 0..7: n-subtile w8*16 of BN=128, K-half [0,256); waves 8..15: same
//    n-subtiles, K-half [256,512). Partials reduced via padded LDS (stride 17,
//    2-way conflicts = free). 16 waves/CU = 4/SIMD (2x round-2 latency hiding).
//  - W streamed global->registers, 2-deep float4x2 prefetch (~64KB/CU in flight,
//    well past the ~9KB BW-latency product -> BW-bound). W read from HBM once.
//  - X slice staged once into LDS as bf16 (64 rows x 512, stride 520 -> b128
//    A-frag reads conflict-free, measured 0 conflicts with this pattern in R1).
//  - K-loop barrier-free; fp32 accum; RTN fp32->bf16 (proven absmax 0.0156).

constexpr int BATCH  = 2048;
constexpr int NAGENT = 64;
constexpr int IN_F   = 512;
constexpr int OUT_F  = 512;

constexpr int BN  = 128;        // block n-tile
constexpr int MCH = 64;         // m rows per chunk (count<=64 in practice; loop covers more)
constexpr int XS  = IN_F + 8;   // X LDS stride in bf16 elems (520)

typedef __attribute__((ext_vector_type(8))) short short8;     // bf16 A/B frag (4 VGPRs)
typedef __attribute__((ext_vector_type(4))) float f32x4;      // fp32 C/D frag
typedef __attribute__((ext_vector_type(4))) unsigned int u32x4;

__device__ inline unsigned rnd_bf(float f) {
  // fp32 -> bf16 RTN, result in high 16 bits
  unsigned u = __float_as_uint(f);
  return u + 0x7FFFu + ((u >> 16) & 1u);
}
__device__ inline unsigned pk_bf(float lo, float hi) {
  return (rnd_bf(lo) >> 16) | (rnd_bf(hi) & 0xFFFF0000u);
}

__global__ __launch_bounds__(1024, 4) void agent_linear_mfma2(
    const int*   __restrict__ which,
    const float* __restrict__ x,
    const float* __restrict__ weight,
    const float* __restrict__ bias,
    float*       __restrict__ out) {
  const int tid   = threadIdx.x;
  const int lane  = tid & 63;
  const int wid   = tid >> 6;        // 0..15
  const int w8    = wid & 7;         // n-wave within BN
  const int kh    = wid >> 3;        // k-half: 0 or 1
  const int agent = blockIdx.y;
  const int obase = blockIdx.x * BN;

  __shared__ int rowlist_s[BATCH];                       // 8 KB
  __shared__ int wsum_s[16];
  __shared__ __align__(16) unsigned short Xs[MCH * XS];  // 65 KB bf16
  __shared__ float Rs[8][MCH][17];                       // 34 KB, k-half partials

  // ---- stable compaction: rows with which[i]==agent, ascending ----
  int2 v = ((const int2*)which)[tid];                    // 2 vals/thread, 1024 threads
  int lc = (v.x == agent) + (v.y == agent);
  int s = lc;
#pragma unroll
  for (int off = 1; off < 64; off <<= 1) {
    int t = __shfl_up(s, off);
    if (lane >= off) s += t;
  }
  if (lane == 63) wsum_s[wid] = s;
  __syncthreads();
  int base = 0, count = 0;
#pragma unroll
  for (int w = 0; w < 16; ++w) {
    int ws = wsum_s[w];
    if (w < wid) base += ws;
    count += ws;
  }
  {
    int pos = base + s - lc;
    if (v.x == agent) rowlist_s[pos++] = 2 * tid;
    if (v.y == agent) rowlist_s[pos]   = 2 * tid + 1;
  }

  const int nl = lane & 15;      // n within frag / m within A-frag
  const int kq = lane >> 4;      // k-quad 0..3

  const float* wp = weight + ((size_t)(agent * OUT_F + obase + w8 * 16 + nl)) * IN_F
                  + kh * 256 + kq * 8;
  const float  bv = bias[agent * OUT_F + obase + w8 * 16 + nl];

  for (int m0 = 0; m0 < count; m0 += MCH) {
    const int mcount = min(MCH, count - m0);
    __syncthreads();   // rowlist ready / prior iter's Xs+Rs reads done

    // ---- stage X chunk: 64 rows x 512 k as bf16 ----
#pragma unroll
    for (int t = 0; t < 8; ++t) {
      int idx = t * 1024 + tid;
      int r   = idx >> 7;          // 0..63
      int c4  = idx & 127;         // float4 column
      uint2 w2 = {0u, 0u};
      if (r < mcount) {
        float4 xv = *(const float4*)(x + (size_t)rowlist_s[m0 + r] * IN_F + c4 * 4);
        w2.x = pk_bf(xv.x, xv.y);
        w2.y = pk_bf(xv.z, xv.w);
      }
      *(uint2*)&Xs[r * XS + c4 * 4] = w2;
    }
    __syncthreads();

    // ---- barrier-free K-loop over this wave's 256-k half ----
    f32x4 acc[4] = {{0.f,0.f,0.f,0.f},{0.f,0.f,0.f,0.f},
                    {0.f,0.f,0.f,0.f},{0.f,0.f,0.f,0.f}};
    const int kbase = kh * 256;
    float4 pa[2], pb[2];
    pa[0] = *(const float4*)(wp);      pb[0] = *(const float4*)(wp + 4);
    pa[1] = *(const float4*)(wp + 32); pb[1] = *(const float4*)(wp + 36);
#pragma unroll
    for (int k = 0; k < 8; ++k) {
      float4 c0 = pa[k & 1], c1 = pb[k & 1];
      if (k + 2 < 8) {
        pa[k & 1] = *(const float4*)(wp + (k + 2) * 32);
        pb[k & 1] = *(const float4*)(wp + (k + 2) * 32 + 4);
      }
      u32x4 q;
      q[0] = pk_bf(c0.x, c0.y); q[1] = pk_bf(c0.z, c0.w);
      q[2] = pk_bf(c1.x, c1.y); q[3] = pk_bf(c1.z, c1.w);
      short8 bf = __builtin_bit_cast(short8, q);
#pragma unroll
      for (int i = 0; i < 4; ++i) {
        short8 af = *(const short8*)&Xs[(i * 16 + nl) * XS + kbase + k * 32 + kq * 8];
        acc[i] = __builtin_amdgcn_mfma_f32_16x16x32_bf16(af, bf, acc[i], 0, 0, 0);
      }
    }

    // ---- cross-k-half reduction: upper waves park partials in LDS ----
    if (kh == 1) {
#pragma unroll
      for (int i = 0; i < 4; ++i)
#pragma unroll
        for (int r = 0; r < 4; ++r)
          Rs[w8][i * 16 + kq * 4 + r][nl] = acc[i][r];
    }
    __syncthreads();

    // ---- epilogue by lower waves: D row=(lane>>4)*4+reg, col=lane&15 ----
    if (kh == 0) {
#pragma unroll
      for (int i = 0; i < 4; ++i) {
#pragma unroll
        for (int r = 0; r < 4; ++r) {
          int m = i * 16 + kq * 4 + r;
          if (m < mcount) {
            out[(size_t)rowlist_s[m0 + m] * OUT_F + obase + w8 * 16 + nl] =
                acc[i][r] + Rs[w8][m][nl] + bv;
          }
        }
      }
    }
  }
}

extern "C" void kernel_launch(void* const* d_in, const int* in_sizes, int n_in,
                              void* d_out, int out_size, void* d_ws, size_t ws_size,
                              hipStream_t stream) {
  const int*   which = (const int*)d_in[0];
  const float* x     = (const float*)d_in[1];
  const float* w     = (const float*)d_in[2];
  const float* b     = (const float*)d_in[3];
  float*       out   = (float*)d_out;

  dim3 grid(OUT_F / BN, NAGENT);   // 4 x 64 = 256 blocks, 1 per CU
  agent_linear_mfma2<<<grid, dim3(1024), 0, stream>>>(which, x, w, b, out);
}